// Round 1
// baseline (1001.686 us; speedup 1.0000x reference)
//
#include <hip/hip_runtime.h>
#include <math.h>

// Problem constants (from reference): B=2, N=2048, C=1024, H=4096, E=8, K=2
#define TT  4096      // tokens = B*N
#define CC  1024
#define HH  4096
#define EE  8
#define TKN 8192      // T*K total expert-row assignments

typedef _Float16 f16x8 __attribute__((ext_vector_type(8)));
typedef float    f32x4 __attribute__((ext_vector_type(4)));

// async global->LDS DMA, 16B per lane; LDS dest = wave-uniform base + lane*16
#define GLD_LDS16(g, l)                                                        \
    __builtin_amdgcn_global_load_lds(                                          \
        (const __attribute__((address_space(1))) void*)(g),                    \
        (__attribute__((address_space(3))) void*)(l), 16, 0, 0)

// ---------------------------------------------------------------------------
// Kernel 1: gating. One wave per token. fp64 logits so top-2 selection matches
// the numpy reference (selection flips on near-ties would exceed threshold).
// ---------------------------------------------------------------------------
__global__ __launch_bounds__(256) void gate_kernel(
    const float* __restrict__ x, const float* __restrict__ gn,
    const float* __restrict__ gw, const float* __restrict__ gb,
    int* __restrict__ topk_idx, float* __restrict__ topk_w,
    int* __restrict__ counts, float* __restrict__ gsum)
{
    int wave = threadIdx.x >> 6, lane = threadIdx.x & 63;
    int t = blockIdx.x * 4 + wave;
    const float* xrow = x + (size_t)t * CC;

    double acc[EE];
#pragma unroll
    for (int e = 0; e < EE; e++) acc[e] = 0.0;

#pragma unroll
    for (int i = 0; i < CC / 64; i++) {
        int c = i * 64 + lane;
        float xv = xrow[c];                       // coalesced
        const float4* g4 = reinterpret_cast<const float4*>(gw + (size_t)c * EE);
        float4 g0 = g4[0], g1 = g4[1];            // gate_w row c (8 floats)
        double xd = (double)xv;
        acc[0] += xd * (double)g0.x; acc[1] += xd * (double)g0.y;
        acc[2] += xd * (double)g0.z; acc[3] += xd * (double)g0.w;
        acc[4] += xd * (double)g1.x; acc[5] += xd * (double)g1.y;
        acc[6] += xd * (double)g1.z; acc[7] += xd * (double)g1.w;
    }
    // butterfly reduce over 64 lanes; all lanes end with full sums
#pragma unroll
    for (int e = 0; e < EE; e++)
#pragma unroll
        for (int off = 32; off > 0; off >>= 1)
            acc[e] += __shfl_xor(acc[e], off);

    double z[EE], m = -1e300;
#pragma unroll
    for (int e = 0; e < EE; e++) {
        z[e] = acc[e] + (double)gb[e] + (double)gn[(size_t)t * EE + e];
        m = fmax(m, z[e]);
    }
    double p[EE], s = 0.0;
#pragma unroll
    for (int e = 0; e < EE; e++) { p[e] = exp(z[e] - m); s += p[e]; }
    double inv = 1.0 / s;
    double g[EE];
#pragma unroll
    for (int e = 0; e < EE; e++) g[e] = p[e] * inv;

    // top-2, ties -> lower index first (matches jax.lax.top_k)
    int i1 = 0; double v1 = g[0];
#pragma unroll
    for (int e = 1; e < EE; e++) if (g[e] > v1) { v1 = g[e]; i1 = e; }
    int i2 = -1; double v2 = -1.0;
#pragma unroll
    for (int e = 0; e < EE; e++) if (e != i1 && g[e] > v2) { v2 = g[e]; i2 = e; }

    if (lane == 0) {
        topk_idx[t * 2 + 0] = i1; topk_w[t * 2 + 0] = (float)v1;
        topk_idx[t * 2 + 1] = i2; topk_w[t * 2 + 1] = (float)v2;
        atomicAdd(&counts[i1], 1);
        atomicAdd(&counts[i2], 1);
    }

    // per-block gate-sum reduction -> 8 atomics per block
    __shared__ float gp[4][EE];
    if (lane == 0) {
#pragma unroll
        for (int e = 0; e < EE; e++) gp[wave][e] = (float)g[e];
    }
    __syncthreads();
    if (threadIdx.x < EE) {
        float s4 = gp[0][threadIdx.x] + gp[1][threadIdx.x] +
                   gp[2][threadIdx.x] + gp[3][threadIdx.x];
        atomicAdd(&gsum[threadIdx.x], s4);
    }
}

// ---------------------------------------------------------------------------
// Kernel 2: fused transpose + f32->f16 cast for expert weights.
// src: [E][R][Ccols] f32 row-major  ->  dst: [E][Ccols][R] f16 row-major
// 256 linear threads; loads float4 (16B/lane), stores 2x f16x8 (32B/thread).
// ---------------------------------------------------------------------------
__global__ __launch_bounds__(256) void transpose_f16_kernel(
    const float* __restrict__ src, _Float16* __restrict__ dst, int R, int Ccols)
{
    __shared__ float tile[64][65];
    int e = blockIdx.z;
    const float* s = src + (size_t)e * R * Ccols;
    _Float16* d = dst + (size_t)e * R * Ccols;
    int c0 = blockIdx.x * 64, r0 = blockIdx.y * 64;
    int tid = threadIdx.x;

    int lr = tid >> 4;            // 0..15
    int lc = (tid & 15) * 4;      // 0..60
#pragma unroll
    for (int i = 0; i < 4; i++) {
        int r = lr + i * 16;
        float4 v = *reinterpret_cast<const float4*>(
            s + (size_t)(r0 + r) * Ccols + c0 + lc);
        tile[r][lc + 0] = v.x; tile[r][lc + 1] = v.y;
        tile[r][lc + 2] = v.z; tile[r][lc + 3] = v.w;
    }
    __syncthreads();

    int oc = tid >> 2;            // 0..63  (output row = source column)
    int orr = (tid & 3) * 16;     // 0..48
    f16x8 o0, o1;
#pragma unroll
    for (int j = 0; j < 8; j++) o0[j] = (_Float16)tile[orr + j][oc];
#pragma unroll
    for (int j = 0; j < 8; j++) o1[j] = (_Float16)tile[orr + 8 + j][oc];
    *reinterpret_cast<f16x8*>(d + (size_t)(c0 + oc) * R + r0 + orr)     = o0;
    *reinterpret_cast<f16x8*>(d + (size_t)(c0 + oc) * R + r0 + orr + 8) = o1;
}

// ---------------------------------------------------------------------------
// Kernel 3: tiny scan — prefix-sum counts into offsets; load-balance loss.
// ---------------------------------------------------------------------------
__global__ void scan_kernel(const int* __restrict__ counts, int* __restrict__ offsets,
                            const float* __restrict__ gsum, float* __restrict__ loss_out)
{
    if (threadIdx.x == 0) {
        int o = 0;
#pragma unroll
        for (int e = 0; e < EE; e++) { offsets[e] = o; o += counts[e]; }
        offsets[EE] = o;   // == TKN
        float L = 0.f;
#pragma unroll
        for (int e = 0; e < EE; e++) {
            float me = gsum[e] / (float)TT;
            L += me * logf(me + 1e-8f);
        }
        *loss_out = L;
    }
}

// ---------------------------------------------------------------------------
// Kernel 4: scatter token assignments into per-expert contiguous segments.
// Also records the inverse map posmap[t*2+k] = segment position, so the
// combine kernel can gather y rows without atomics.
// ---------------------------------------------------------------------------
__global__ __launch_bounds__(256) void scatter_kernel(
    const int* __restrict__ topk_idx, const int* __restrict__ offsets,
    int* __restrict__ fill, int* __restrict__ rowtok, int* __restrict__ posmap)
{
    int t = blockIdx.x * 256 + threadIdx.x;
#pragma unroll
    for (int k = 0; k < 2; k++) {
        int e = topk_idx[t * 2 + k];
        int pos = offsets[e] + atomicAdd(&fill[e], 1);
        rowtok[pos] = t;
        posmap[t * 2 + k] = pos;
    }
}

// ---------------------------------------------------------------------------
// Kernel 5: pre-gather token rows into segment order + f32->f16 cast.
// ---------------------------------------------------------------------------
__global__ __launch_bounds__(256) void gather_kernel(
    const float* __restrict__ x, const int* __restrict__ rowtok,
    _Float16* __restrict__ xg)
{
    int p = blockIdx.x * 2 + (threadIdx.x >> 7);
    int c = (threadIdx.x & 127) * 8;
    int t = rowtok[p];
    const float4* s = reinterpret_cast<const float4*>(x + (size_t)t * CC + c);
    float4 v0 = s[0], v1 = s[1];
    f16x8 o;
    o[0] = (_Float16)v0.x; o[1] = (_Float16)v0.y;
    o[2] = (_Float16)v0.z; o[3] = (_Float16)v0.w;
    o[4] = (_Float16)v1.x; o[5] = (_Float16)v1.y;
    o[6] = (_Float16)v1.z; o[7] = (_Float16)v1.w;
    *reinterpret_cast<f16x8*>(xg + (size_t)p * CC + c) = o;
}

// ---------------------------------------------------------------------------
// Grouped GEMM 1: h[p, :] = gelu( xg[p, :] @ w1[e] + b1[e] )  (f16 MFMA)
// 128x128 tile, BK=64, global_load_lds(16B), double-buffered LDS (T3
// minimum 2-phase: STAGE(next) issued before compute(cur), ONE barrier/iter),
// bijective XCD swizzle (T1) so the 12 m-tiles sharing a B-panel co-locate.
// ---------------------------------------------------------------------------
__global__ __launch_bounds__(256) void gemm1_kernel(
    const _Float16* __restrict__ xg, const _Float16* __restrict__ w1t,
    const float* __restrict__ b1, const int* __restrict__ offsets,
    _Float16* __restrict__ h)
{
    // XCD swizzle: hw flat id f runs round-robin over XCDs (f%8); remap so
    // tile chunk [k*cpx,(k+1)*cpx) lands entirely on XCD k. nwg%8==0.
    int GX = gridDim.x, GY = gridDim.y;
    int nwg = GX * GY * (int)gridDim.z;
    int f = blockIdx.x + GX * (blockIdx.y + GY * blockIdx.z);
    int cpx = nwg >> 3;
    f = (f & 7) * cpx + (f >> 3);
    int bx = f % GX; int tq = f / GX; int by = tq % GY; int bz = tq / GY;

    int e = bz;
    int segs = offsets[e];
    int M = offsets[e + 1] - segs;
    int m0 = bx * 128;
    if (m0 >= M) return;
    int n0 = by * 128;

    __shared__ __align__(16) _Float16 As[2][128][64];
    __shared__ __align__(16) _Float16 Bs[2][128][64];

    int tid = threadIdx.x;
    int wave = tid >> 6, lane = tid & 63;
    int wm = (wave >> 1) * 64, wn = (wave & 1) * 64;
    int lrow = lane & 15, kg = lane >> 4;

    const _Float16* wB = w1t + (size_t)e * HH * CC;

    const _Float16* ap[4]; const _Float16* bp[4];
    int lofs[4];
#pragma unroll
    for (int j = 0; j < 4; j++) {
        int ch = (wave * 4 + j) * 64 + lane;      // 0..1023
        int row = ch >> 3, kc = ch & 7;
        int rm = m0 + row; if (rm >= M) rm = M - 1;   // clamp: stays in segment
        ap[j] = xg + (size_t)(segs + rm) * CC + kc * 8;
        bp[j] = wB + (size_t)(n0 + row) * CC + kc * 8;
        lofs[j] = ch * 8;
    }

    f32x4 acc[4][4];
#pragma unroll
    for (int i = 0; i < 4; i++)
#pragma unroll
        for (int j = 0; j < 4; j++)
#pragma unroll
            for (int r = 0; r < 4; r++) acc[i][j][r] = 0.f;

    _Float16* A0 = &As[0][0][0];
    _Float16* B0 = &Bs[0][0][0];

    // prologue: stage K-tile 0 into buffer 0, drain, barrier
#pragma unroll
    for (int j = 0; j < 4; j++) {
        GLD_LDS16(ap[j], A0 + lofs[j]);
        GLD_LDS16(bp[j], B0 + lofs[j]);
        ap[j] += 64; bp[j] += 64;
    }
    __syncthreads();

    int cur = 0;
    const int NIT = CC / 64;   // 16
    for (int it = 0; it < NIT; ++it) {
        if (it + 1 < NIT) {        // issue next-tile loads FIRST (overlap)
            _Float16* ad = A0 + (cur ^ 1) * (128 * 64);
            _Float16* bd = B0 + (cur ^ 1) * (128 * 64);
#pragma unroll
            for (int j = 0; j < 4; j++) {
                GLD_LDS16(ap[j], ad + lofs[j]);
                GLD_LDS16(bp[j], bd + lofs[j]);
                ap[j] += 64; bp[j] += 64;
            }
        }
        const _Float16* Ac = A0 + cur * (128 * 64);
        const _Float16* Bc = B0 + cur * (128 * 64);
        f16x8 aF[2][4], bF[2][4];
#pragma unroll
        for (int s = 0; s < 2; s++)
#pragma unroll
            for (int i = 0; i < 4; i++) {
                aF[s][i] = *reinterpret_cast<const f16x8*>(
                    Ac + (wm + i * 16 + lrow) * 64 + s * 32 + kg * 8);
                bF[s][i] = *reinterpret_cast<const f16x8*>(
                    Bc + (wn + i * 16 + lrow) * 64 + s * 32 + kg * 8);
            }
#pragma unroll
        for (int s = 0; s < 2; s++)
#pragma unroll
            for (int mi = 0; mi < 4; mi++)
#pragma unroll
                for (int ni = 0; ni < 4; ni++)
                    acc[mi][ni] = __builtin_amdgcn_mfma_f32_16x16x32_f16(
                        aF[s][mi], bF[s][ni], acc[mi][ni], 0, 0, 0);
        __syncthreads();   // one barrier/iter: drains vmcnt (next buf ready)
        cur ^= 1;
    }

    // epilogue: C/D layout col=lane&15, row=(lane>>4)*4+reg  [m89/m91]
    int rbase = (lane >> 4) * 4;
#pragma unroll
    for (int mi = 0; mi < 4; mi++) {
#pragma unroll
        for (int ni = 0; ni < 4; ni++) {
            int gcol = n0 + wn + ni * 16 + lrow;
            float bias = b1[(size_t)e * HH + gcol];
#pragma unroll
            for (int r = 0; r < 4; r++) {
                int rowl = m0 + wm + mi * 16 + rbase + r;
                if (rowl < M) {
                    float v = acc[mi][ni][r] + bias;
                    v = 0.5f * v * (1.0f + erff(v * 0.70710678118654752f)); // exact GELU
                    h[(size_t)(segs + rowl) * HH + gcol] = (_Float16)v;
                }
            }
        }
    }
}

// ---------------------------------------------------------------------------
// Grouped GEMM 2 (no split-K, no atomics): y[p, :] = h[p,:] @ w2[e] + b2[e]
// Plain f32 row stores in segment order; weighting+combine done in
// combine_kernel. Same T3 2-phase pipeline + T1 swizzle as gemm1.
// ---------------------------------------------------------------------------
__global__ __launch_bounds__(256) void gemm2_kernel(
    const _Float16* __restrict__ h, const _Float16* __restrict__ w2t,
    const float* __restrict__ b2, const int* __restrict__ offsets,
    float* __restrict__ y)
{
    int GX = gridDim.x, GY = gridDim.y;
    int nwg = GX * GY * (int)gridDim.z;    // 12*8*8 = 768, %8==0
    int f = blockIdx.x + GX * (blockIdx.y + GY * blockIdx.z);
    int cpx = nwg >> 3;
    f = (f & 7) * cpx + (f >> 3);
    int bx = f % GX; int tq = f / GX; int by = tq % GY; int bz = tq / GY;

    int e = bz;
    int segs = offsets[e];
    int M = offsets[e + 1] - segs;
    int m0 = bx * 128;
    if (m0 >= M) return;
    int n0 = by * 128;

    __shared__ __align__(16) _Float16 As[2][128][64];
    __shared__ __align__(16) _Float16 Bs[2][128][64];

    int tid = threadIdx.x;
    int wave = tid >> 6, lane = tid & 63;
    int wm = (wave >> 1) * 64, wn = (wave & 1) * 64;
    int lrow = lane & 15, kg = lane >> 4;

    const _Float16* wB = w2t + (size_t)e * CC * HH;

    const _Float16* ap[4]; const _Float16* bp[4];
    int lofs[4];
#pragma unroll
    for (int j = 0; j < 4; j++) {
        int ch = (wave * 4 + j) * 64 + lane;
        int row = ch >> 3, kc = ch & 7;
        int rm = m0 + row; if (rm >= M) rm = M - 1;
        ap[j] = h  + (size_t)(segs + rm) * HH + kc * 8;
        bp[j] = wB + (size_t)(n0 + row) * HH + kc * 8;
        lofs[j] = ch * 8;
    }

    f32x4 acc[4][4];
#pragma unroll
    for (int i = 0; i < 4; i++)
#pragma unroll
        for (int j = 0; j < 4; j++)
#pragma unroll
            for (int r = 0; r < 4; r++) acc[i][j][r] = 0.f;

    _Float16* A0 = &As[0][0][0];
    _Float16* B0 = &Bs[0][0][0];

#pragma unroll
    for (int j = 0; j < 4; j++) {
        GLD_LDS16(ap[j], A0 + lofs[j]);
        GLD_LDS16(bp[j], B0 + lofs[j]);
        ap[j] += 64; bp[j] += 64;
    }
    __syncthreads();

    int cur = 0;
    const int NIT = HH / 64;   // 64
    for (int it = 0; it < NIT; ++it) {
        if (it + 1 < NIT) {
            _Float16* ad = A0 + (cur ^ 1) * (128 * 64);
            _Float16* bd = B0 + (cur ^ 1) * (128 * 64);
#pragma unroll
            for (int j = 0; j < 4; j++) {
                GLD_LDS16(ap[j], ad + lofs[j]);
                GLD_LDS16(bp[j], bd + lofs[j]);
                ap[j] += 64; bp[j] += 64;
            }
        }
        const _Float16* Ac = A0 + cur * (128 * 64);
        const _Float16* Bc = B0 + cur * (128 * 64);
        f16x8 aF[2][4], bF[2][4];
#pragma unroll
        for (int s = 0; s < 2; s++)
#pragma unroll
            for (int i = 0; i < 4; i++) {
                aF[s][i] = *reinterpret_cast<const f16x8*>(
                    Ac + (wm + i * 16 + lrow) * 64 + s * 32 + kg * 8);
                bF[s][i] = *reinterpret_cast<const f16x8*>(
                    Bc + (wn + i * 16 + lrow) * 64 + s * 32 + kg * 8);
            }
#pragma unroll
        for (int s = 0; s < 2; s++)
#pragma unroll
            for (int mi = 0; mi < 4; mi++)
#pragma unroll
                for (int ni = 0; ni < 4; ni++)
                    acc[mi][ni] = __builtin_amdgcn_mfma_f32_16x16x32_f16(
                        aF[s][mi], bF[s][ni], acc[mi][ni], 0, 0, 0);
        __syncthreads();
        cur ^= 1;
    }

    int rbase = (lane >> 4) * 4;
#pragma unroll
    for (int mi = 0; mi < 4; mi++) {
#pragma unroll
        for (int ni = 0; ni < 4; ni++) {
            int gcol = n0 + wn + ni * 16 + lrow;
            float bias = b2[(size_t)e * CC + gcol];
#pragma unroll
            for (int r = 0; r < 4; r++) {
                int rowl = m0 + wm + mi * 16 + rbase + r;
                if (rowl < M)
                    y[(size_t)(segs + rowl) * CC + gcol] = acc[mi][ni][r] + bias;
            }
        }
    }
}

// ---------------------------------------------------------------------------
// Kernel 8: combine. out[t,:] = w0*y[pos0(t),:] + w1*y[pos1(t),:]
// Fully coalesced float4 loads/stores; replaces 16.8M device atomics.
// ---------------------------------------------------------------------------
__global__ __launch_bounds__(256) void combine_kernel(
    const float* __restrict__ y, const int* __restrict__ posmap,
    const float* __restrict__ topk_w, float* __restrict__ out)
{
    int t = blockIdx.x * 2 + (threadIdx.x >> 7);
    int c = (threadIdx.x & 127) * 8;
    int p0 = posmap[t * 2 + 0], p1 = posmap[t * 2 + 1];
    float wa = topk_w[t * 2 + 0], wb = topk_w[t * 2 + 1];
    const float4* a = reinterpret_cast<const float4*>(y + (size_t)p0 * CC + c);
    const float4* b = reinterpret_cast<const float4*>(y + (size_t)p1 * CC + c);
    float4 a0 = a[0], a1 = a[1], b0 = b[0], b1 = b[1];
    float4 r0, r1;
    r0.x = wa * a0.x + wb * b0.x; r0.y = wa * a0.y + wb * b0.y;
    r0.z = wa * a0.z + wb * b0.z; r0.w = wa * a0.w + wb * b0.w;
    r1.x = wa * a1.x + wb * b1.x; r1.y = wa * a1.y + wb * b1.y;
    r1.z = wa * a1.z + wb * b1.z; r1.w = wa * a1.w + wb * b1.w;
    float4* o = reinterpret_cast<float4*>(out + (size_t)t * CC + c);
    o[0] = r0; o[1] = r1;
}

// ---------------------------------------------------------------------------
extern "C" void kernel_launch(void* const* d_in, const int* in_sizes, int n_in,
                              void* d_out, int out_size, void* d_ws, size_t ws_size,
                              hipStream_t stream)
{
    const float* x  = (const float*)d_in[0];
    const float* gn = (const float*)d_in[1];
    const float* gw = (const float*)d_in[2];
    const float* gb = (const float*)d_in[3];
    const float* w1 = (const float*)d_in[4];
    const float* b1 = (const float*)d_in[5];
    const float* w2 = (const float*)d_in[6];
    const float* b2 = (const float*)d_in[7];
    float* out = (float*)d_out;

    // workspace carve (all 16B-aligned; ~208 MB total, same as baseline)
    char* w = (char*)d_ws;
    int*   counts  = (int*)(w + 0);     // 8 ints
    int*   fill    = (int*)(w + 32);    // 8 ints
    int*   offsets = (int*)(w + 64);    // 9 ints
    float* gsum    = (float*)(w + 128); // 8 floats
    size_t off = 256;
    int*   topk_idx = (int*)(w + off);   off += (size_t)TT * 2 * 4;
    float* topk_w   = (float*)(w + off); off += (size_t)TT * 2 * 4;
    int*   rowtok   = (int*)(w + off);   off += (size_t)TKN * 4;
    int*   posmap   = (int*)(w + off);   off += (size_t)TKN * 4;
    _Float16* xg  = (_Float16*)(w + off); off += (size_t)TKN * CC * 2;      // 16 MB
    _Float16* w1t = (_Float16*)(w + off); off += (size_t)EE * HH * CC * 2;  // 64 MB
    _Float16* w2t = (_Float16*)(w + off); off += (size_t)EE * CC * HH * 2;  // 64 MB
    _Float16* hbuf = (_Float16*)(w + off); off += (size_t)TKN * HH * 2;     // 64 MB
    // y overlays w1t: w1t is dead after gemm1, and the transpose rewrites it
    // at the start of every launch (stream order makes this safe in capture).
    float* ybuf = (float*)w1t;           // needs TKN*CC*4 = 32 MB <= 64 MB

    (void)hipMemsetAsync(d_ws, 0, 256, stream);

    gate_kernel<<<TT / 4, 256, 0, stream>>>(x, gn, gw, gb, topk_idx, topk_w,
                                            counts, gsum);
    // w1 [E,C,H] -> w1t [E,H,C];  w2 [E,H,C] -> w2t [E,C,H]
    transpose_f16_kernel<<<dim3(HH / 64, CC / 64, EE), 256, 0, stream>>>(
        w1, w1t, CC, HH);
    transpose_f16_kernel<<<dim3(CC / 64, HH / 64, EE), 256, 0, stream>>>(
        w2, w2t, HH, CC);
    scan_kernel<<<1, 64, 0, stream>>>(counts, offsets, gsum, out + (size_t)TT * CC);
    scatter_kernel<<<TT / 256, 256, 0, stream>>>(topk_idx, offsets, fill,
                                                 rowtok, posmap);
    gather_kernel<<<TKN / 2, 256, 0, stream>>>(x, rowtok, xg);
    // grid.x=12 covers M_e up to 1536 (E[M_e]=1024, sigma~30; early-exit rest)
    gemm1_kernel<<<dim3(12, HH / 128, EE), 256, 0, stream>>>(xg, w1t, b1,
                                                             offsets, hbuf);
    gemm2_kernel<<<dim3(12, CC / 128, EE), 256, 0, stream>>>(
        hbuf, w2t, b2, offsets, ybuf);
    combine_kernel<<<TT / 2, 256, 0, stream>>>(ybuf, posmap, topk_w, out);
}

// Round 2
// 876.308 us; speedup vs baseline: 1.1431x; 1.1431x over previous
//
#include <hip/hip_runtime.h>
#include <math.h>

// Problem constants (from reference): B=2, N=2048, C=1024, H=4096, E=8, K=2
#define TT  4096      // tokens = B*N
#define CC  1024
#define HH  4096
#define EE  8
#define TKN 8192      // T*K total expert-row assignments

typedef _Float16 f16x8 __attribute__((ext_vector_type(8)));
typedef float    f32x4 __attribute__((ext_vector_type(4)));

// async global->LDS DMA, 16B per lane; LDS dest = wave-uniform base + lane*16
#define GLD_LDS16(g, l)                                                        \
    __builtin_amdgcn_global_load_lds(                                          \
        (const __attribute__((address_space(1))) void*)(g),                    \
        (__attribute__((address_space(3))) void*)(l), 16, 0, 0)

// counted-vmcnt boundary: NO __syncthreads (it would drain vmcnt(0))
#define BOUNDARY(N)                                                            \
    do {                                                                       \
        asm volatile("s_waitcnt vmcnt(" #N ")" ::: "memory");                  \
        __builtin_amdgcn_s_barrier();                                          \
    } while (0)

// ---------------------------------------------------------------------------
// Kernel 1: gating. One wave per token. fp64 logits so top-2 selection matches
// the numpy reference (selection flips on near-ties would exceed threshold).
// ---------------------------------------------------------------------------
__global__ __launch_bounds__(256) void gate_kernel(
    const float* __restrict__ x, const float* __restrict__ gn,
    const float* __restrict__ gw, const float* __restrict__ gb,
    int* __restrict__ topk_idx, float* __restrict__ topk_w,
    int* __restrict__ counts, float* __restrict__ gsum)
{
    int wave = threadIdx.x >> 6, lane = threadIdx.x & 63;
    int t = blockIdx.x * 4 + wave;
    const float* xrow = x + (size_t)t * CC;

    double acc[EE];
#pragma unroll
    for (int e = 0; e < EE; e++) acc[e] = 0.0;

#pragma unroll
    for (int i = 0; i < CC / 64; i++) {
        int c = i * 64 + lane;
        float xv = xrow[c];                       // coalesced
        const float4* g4 = reinterpret_cast<const float4*>(gw + (size_t)c * EE);
        float4 g0 = g4[0], g1 = g4[1];            // gate_w row c (8 floats)
        double xd = (double)xv;
        acc[0] += xd * (double)g0.x; acc[1] += xd * (double)g0.y;
        acc[2] += xd * (double)g0.z; acc[3] += xd * (double)g0.w;
        acc[4] += xd * (double)g1.x; acc[5] += xd * (double)g1.y;
        acc[6] += xd * (double)g1.z; acc[7] += xd * (double)g1.w;
    }
    // butterfly reduce over 64 lanes; all lanes end with full sums
#pragma unroll
    for (int e = 0; e < EE; e++)
#pragma unroll
        for (int off = 32; off > 0; off >>= 1)
            acc[e] += __shfl_xor(acc[e], off);

    double z[EE], m = -1e300;
#pragma unroll
    for (int e = 0; e < EE; e++) {
        z[e] = acc[e] + (double)gb[e] + (double)gn[(size_t)t * EE + e];
        m = fmax(m, z[e]);
    }
    double p[EE], s = 0.0;
#pragma unroll
    for (int e = 0; e < EE; e++) { p[e] = exp(z[e] - m); s += p[e]; }
    double inv = 1.0 / s;
    double g[EE];
#pragma unroll
    for (int e = 0; e < EE; e++) g[e] = p[e] * inv;

    // top-2, ties -> lower index first (matches jax.lax.top_k)
    int i1 = 0; double v1 = g[0];
#pragma unroll
    for (int e = 1; e < EE; e++) if (g[e] > v1) { v1 = g[e]; i1 = e; }
    int i2 = -1; double v2 = -1.0;
#pragma unroll
    for (int e = 0; e < EE; e++) if (e != i1 && g[e] > v2) { v2 = g[e]; i2 = e; }

    if (lane == 0) {
        topk_idx[t * 2 + 0] = i1; topk_w[t * 2 + 0] = (float)v1;
        topk_idx[t * 2 + 1] = i2; topk_w[t * 2 + 1] = (float)v2;
        atomicAdd(&counts[i1], 1);
        atomicAdd(&counts[i2], 1);
    }

    // per-block gate-sum reduction -> 8 atomics per block
    __shared__ float gp[4][EE];
    if (lane == 0) {
#pragma unroll
        for (int e = 0; e < EE; e++) gp[wave][e] = (float)g[e];
    }
    __syncthreads();
    if (threadIdx.x < EE) {
        float s4 = gp[0][threadIdx.x] + gp[1][threadIdx.x] +
                   gp[2][threadIdx.x] + gp[3][threadIdx.x];
        atomicAdd(&gsum[threadIdx.x], s4);
    }
}

// ---------------------------------------------------------------------------
// Kernel 2: fused transpose + f32->f16 cast for expert weights.
// src: [E][R][Ccols] f32 row-major  ->  dst: [E][Ccols][R] f16 row-major
// ---------------------------------------------------------------------------
__global__ __launch_bounds__(256) void transpose_f16_kernel(
    const float* __restrict__ src, _Float16* __restrict__ dst, int R, int Ccols)
{
    __shared__ float tile[64][65];
    int e = blockIdx.z;
    const float* s = src + (size_t)e * R * Ccols;
    _Float16* d = dst + (size_t)e * R * Ccols;
    int c0 = blockIdx.x * 64, r0 = blockIdx.y * 64;
    int tid = threadIdx.x;

    int lr = tid >> 4;            // 0..15
    int lc = (tid & 15) * 4;      // 0..60
#pragma unroll
    for (int i = 0; i < 4; i++) {
        int r = lr + i * 16;
        float4 v = *reinterpret_cast<const float4*>(
            s + (size_t)(r0 + r) * Ccols + c0 + lc);
        tile[r][lc + 0] = v.x; tile[r][lc + 1] = v.y;
        tile[r][lc + 2] = v.z; tile[r][lc + 3] = v.w;
    }
    __syncthreads();

    int oc = tid >> 2;            // 0..63  (output row = source column)
    int orr = (tid & 3) * 16;     // 0..48
    f16x8 o0, o1;
#pragma unroll
    for (int j = 0; j < 8; j++) o0[j] = (_Float16)tile[orr + j][oc];
#pragma unroll
    for (int j = 0; j < 8; j++) o1[j] = (_Float16)tile[orr + 8 + j][oc];
    *reinterpret_cast<f16x8*>(d + (size_t)(c0 + oc) * R + r0 + orr)     = o0;
    *reinterpret_cast<f16x8*>(d + (size_t)(c0 + oc) * R + r0 + orr + 8) = o1;
}

// ---------------------------------------------------------------------------
// Kernel 3: tiny scan — prefix-sum counts into offsets; load-balance loss.
// ---------------------------------------------------------------------------
__global__ void scan_kernel(const int* __restrict__ counts, int* __restrict__ offsets,
                            const float* __restrict__ gsum, float* __restrict__ loss_out)
{
    if (threadIdx.x == 0) {
        int o = 0;
#pragma unroll
        for (int e = 0; e < EE; e++) { offsets[e] = o; o += counts[e]; }
        offsets[EE] = o;   // == TKN
        float L = 0.f;
#pragma unroll
        for (int e = 0; e < EE; e++) {
            float me = gsum[e] / (float)TT;
            L += me * logf(me + 1e-8f);
        }
        *loss_out = L;
    }
}

// ---------------------------------------------------------------------------
// Kernel 4: scatter token assignments into per-expert contiguous segments.
// posmap[t*2+k] = segment position (inverse map for atomic-free combine).
// ---------------------------------------------------------------------------
__global__ __launch_bounds__(256) void scatter_kernel(
    const int* __restrict__ topk_idx, const int* __restrict__ offsets,
    int* __restrict__ fill, int* __restrict__ rowtok, int* __restrict__ posmap)
{
    int t = blockIdx.x * 256 + threadIdx.x;
#pragma unroll
    for (int k = 0; k < 2; k++) {
        int e = topk_idx[t * 2 + k];
        int pos = offsets[e] + atomicAdd(&fill[e], 1);
        rowtok[pos] = t;
        posmap[t * 2 + k] = pos;
    }
}

// ---------------------------------------------------------------------------
// Kernel 5: pre-gather token rows into segment order + f32->f16 cast.
// ---------------------------------------------------------------------------
__global__ __launch_bounds__(256) void gather_kernel(
    const float* __restrict__ x, const int* __restrict__ rowtok,
    _Float16* __restrict__ xg)
{
    int p = blockIdx.x * 2 + (threadIdx.x >> 7);
    int c = (threadIdx.x & 127) * 8;
    int t = rowtok[p];
    const float4* s = reinterpret_cast<const float4*>(x + (size_t)t * CC + c);
    float4 v0 = s[0], v1 = s[1];
    f16x8 o;
    o[0] = (_Float16)v0.x; o[1] = (_Float16)v0.y;
    o[2] = (_Float16)v0.z; o[3] = (_Float16)v0.w;
    o[4] = (_Float16)v1.x; o[5] = (_Float16)v1.y;
    o[6] = (_Float16)v1.z; o[7] = (_Float16)v1.w;
    *reinterpret_cast<f16x8*>(xg + (size_t)p * CC + c) = o;
}

// ---------------------------------------------------------------------------
// Grouped GEMM 1: h[p,:] = gelu( xg[p,:] @ w1[e] + b1[e] )
// BM=BN=256, BK=32, 512 threads (8 waves as 2Mx4N, per-wave 128x64 output).
// 4-deep LDS ring (4 x 32KB): while computing tile t, stage tile t+3 via
// global_load_lds; ONE raw s_barrier + counted vmcnt(8) per K-tile (no
// __syncthreads -> no vmcnt(0) drain).  BK=32 -> 64B LDS rows: a frag
// ds_read_b128 covers a contiguous 1KB (all banks) -> conflict-free.
// ---------------------------------------------------------------------------
__global__ __launch_bounds__(512, 2) void gemm1_kernel(
    const _Float16* __restrict__ xg, const _Float16* __restrict__ w1t,
    const float* __restrict__ b1, const int* __restrict__ offsets,
    _Float16* __restrict__ h)
{
    // bijective XCD swizzle (nwg = 6*16*8 = 768, %8==0)
    int GX = gridDim.x, GY = gridDim.y;
    int nwg = GX * GY * (int)gridDim.z;
    int f = blockIdx.x + GX * (blockIdx.y + GY * blockIdx.z);
    int cpx = nwg >> 3;
    f = (f & 7) * cpx + (f >> 3);
    int bx = f % GX; int tq = f / GX; int by = tq % GY; int bz = tq / GY;

    int e = bz;
    int segs = offsets[e];
    int M = offsets[e + 1] - segs;
    int m0 = bx * 256;
    if (m0 >= M) return;
    int n0 = by * 256;

    __shared__ __align__(16) _Float16 As[4][256 * 32];   // 4 x 16 KB
    __shared__ __align__(16) _Float16 Bs[4][256 * 32];   // 4 x 16 KB
    _Float16* AsF = &As[0][0];
    _Float16* BsF = &Bs[0][0];

    int tid = threadIdx.x;
    int wave = tid >> 6, lane = tid & 63;
    int wm = (wave >> 2) * 128, wn = (wave & 3) * 64;
    int lrow = lane & 15, kg = lane >> 4;
    int aoff = (wm + lrow) * 32 + kg * 8;
    int boff = (wn + lrow) * 32 + kg * 8;

    const _Float16* wB = w1t + (size_t)e * HH * CC;

    // staging pointers: chunk ch = j*512 + tid; row = ch>>2, c = ch&3
    int r0c = tid >> 2, cc = tid & 3;
    int rmA0 = m0 + r0c;       if (rmA0 >= M) rmA0 = M - 1;
    int rmA1 = m0 + 128 + r0c; if (rmA1 >= M) rmA1 = M - 1;
    const _Float16* ap0 = xg + (size_t)(segs + rmA0) * CC + cc * 8;
    const _Float16* ap1 = xg + (size_t)(segs + rmA1) * CC + cc * 8;
    const _Float16* bp0 = wB + (size_t)(n0 + r0c) * CC + cc * 8;
    const _Float16* bp1 = wB + (size_t)(n0 + 128 + r0c) * CC + cc * 8;
    int c0 = tid * 8;          // LDS elem offset for ch = tid

    f32x4 acc[8][4];
#pragma unroll
    for (int i = 0; i < 8; i++)
#pragma unroll
        for (int j = 0; j < 4; j++)
#pragma unroll
            for (int r = 0; r < 4; r++) acc[i][j][r] = 0.f;

    auto STAGE = [&](int nb) {
        _Float16* ad = AsF + nb * (256 * 32);
        _Float16* bd = BsF + nb * (256 * 32);
        GLD_LDS16(ap0, ad + c0);
        GLD_LDS16(ap1, ad + 4096 + c0);
        GLD_LDS16(bp0, bd + c0);
        GLD_LDS16(bp1, bd + 4096 + c0);
        ap0 += 32; ap1 += 32; bp0 += 32; bp1 += 32;
    };

    auto TILE = [&](int t, bool stage) {
        const _Float16* Ab = AsF + (t & 3) * (256 * 32) + aoff;
        const _Float16* Bb = BsF + (t & 3) * (256 * 32) + boff;
        if (stage) STAGE((t + 3) & 3);
        f16x8 aF[4], bF[4];
#pragma unroll
        for (int j = 0; j < 4; j++)
            bF[j] = *reinterpret_cast<const f16x8*>(Bb + j * 512);
#pragma unroll
        for (int i = 0; i < 4; i++)
            aF[i] = *reinterpret_cast<const f16x8*>(Ab + i * 512);
        __builtin_amdgcn_s_setprio(1);
#pragma unroll
        for (int i = 0; i < 4; i++)
#pragma unroll
            for (int j = 0; j < 4; j++)
                acc[i][j] = __builtin_amdgcn_mfma_f32_16x16x32_f16(
                    aF[i], bF[j], acc[i][j], 0, 0, 0);
        __builtin_amdgcn_s_setprio(0);
#pragma unroll
        for (int i = 0; i < 4; i++)
            aF[i] = *reinterpret_cast<const f16x8*>(Ab + (4 + i) * 512);
        __builtin_amdgcn_s_setprio(1);
#pragma unroll
        for (int i = 0; i < 4; i++)
#pragma unroll
            for (int j = 0; j < 4; j++)
                acc[4 + i][j] = __builtin_amdgcn_mfma_f32_16x16x32_f16(
                    aF[i], bF[j], acc[4 + i][j], 0, 0, 0);
        __builtin_amdgcn_s_setprio(0);
    };

    const int NK = CC / 32;    // 32
    // prologue: stage tiles 0,1,2 into bufs 0,1,2 (12 loads); wait for tile 0
    STAGE(0); STAGE(1); STAGE(2);
    BOUNDARY(8);
    for (int t = 0; t <= NK - 4; ++t) {
        TILE(t, true);         // stages tile t+3 into buf (t+3)&3
        BOUNDARY(8);           // tile t+1 fully landed; 2 tiles in flight
    }
    TILE(NK - 3, false); BOUNDARY(4);
    TILE(NK - 2, false); BOUNDARY(0);
    TILE(NK - 1, false);

    // epilogue: C/D layout col=lane&15, row=(lane>>4)*4+reg  [m89/m91]
    int rbase = (lane >> 4) * 4;
#pragma unroll
    for (int mi = 0; mi < 8; mi++) {
#pragma unroll
        for (int ni = 0; ni < 4; ni++) {
            int gcol = n0 + wn + ni * 16 + lrow;
            float bias = b1[(size_t)e * HH + gcol];
#pragma unroll
            for (int r = 0; r < 4; r++) {
                int rowl = m0 + wm + mi * 16 + rbase + r;
                if (rowl < M) {
                    float v = acc[mi][ni][r] + bias;
                    v = 0.5f * v * (1.0f + erff(v * 0.70710678118654752f)); // exact GELU
                    h[(size_t)(segs + rowl) * HH + gcol] = (_Float16)v;
                }
            }
        }
    }
}

// ---------------------------------------------------------------------------
// Grouped GEMM 2 (split-K=2, no atomics): y[kz][p,:] = h[p,kz*2048:+2048] @
// w2[e][kz-half] (+ b2 when kz==0). Same pipelined structure as gemm1.
// blockIdx.y encodes (kz, n-tile): kz = y>>2, n0 = (y&3)*256.
// ---------------------------------------------------------------------------
__global__ __launch_bounds__(512, 2) void gemm2_kernel(
    const _Float16* __restrict__ h, const _Float16* __restrict__ w2t,
    const float* __restrict__ b2, const int* __restrict__ offsets,
    float* __restrict__ y)
{
    int GX = gridDim.x, GY = gridDim.y;
    int nwg = GX * GY * (int)gridDim.z;    // 6*8*8 = 384, %8==0
    int f = blockIdx.x + GX * (blockIdx.y + GY * blockIdx.z);
    int cpx = nwg >> 3;
    f = (f & 7) * cpx + (f >> 3);
    int bx = f % GX; int tq = f / GX; int by = tq % GY; int bz = tq / GY;

    int e = bz;
    int segs = offsets[e];
    int M = offsets[e + 1] - segs;
    int m0 = bx * 256;
    if (m0 >= M) return;
    int kz = by >> 2;
    int n0 = (by & 3) * 256;
    int kbeg = kz * (HH / 2);

    __shared__ __align__(16) _Float16 As[4][256 * 32];
    __shared__ __align__(16) _Float16 Bs[4][256 * 32];
    _Float16* AsF = &As[0][0];
    _Float16* BsF = &Bs[0][0];

    int tid = threadIdx.x;
    int wave = tid >> 6, lane = tid & 63;
    int wm = (wave >> 2) * 128, wn = (wave & 3) * 64;
    int lrow = lane & 15, kg = lane >> 4;
    int aoff = (wm + lrow) * 32 + kg * 8;
    int boff = (wn + lrow) * 32 + kg * 8;

    const _Float16* wB = w2t + (size_t)e * CC * HH;

    int r0c = tid >> 2, cc = tid & 3;
    int rmA0 = m0 + r0c;       if (rmA0 >= M) rmA0 = M - 1;
    int rmA1 = m0 + 128 + r0c; if (rmA1 >= M) rmA1 = M - 1;
    const _Float16* ap0 = h + (size_t)(segs + rmA0) * HH + kbeg + cc * 8;
    const _Float16* ap1 = h + (size_t)(segs + rmA1) * HH + kbeg + cc * 8;
    const _Float16* bp0 = wB + (size_t)(n0 + r0c) * HH + kbeg + cc * 8;
    const _Float16* bp1 = wB + (size_t)(n0 + 128 + r0c) * HH + kbeg + cc * 8;
    int c0 = tid * 8;

    f32x4 acc[8][4];
#pragma unroll
    for (int i = 0; i < 8; i++)
#pragma unroll
        for (int j = 0; j < 4; j++)
#pragma unroll
            for (int r = 0; r < 4; r++) acc[i][j][r] = 0.f;

    auto STAGE = [&](int nb) {
        _Float16* ad = AsF + nb * (256 * 32);
        _Float16* bd = BsF + nb * (256 * 32);
        GLD_LDS16(ap0, ad + c0);
        GLD_LDS16(ap1, ad + 4096 + c0);
        GLD_LDS16(bp0, bd + c0);
        GLD_LDS16(bp1, bd + 4096 + c0);
        ap0 += 32; ap1 += 32; bp0 += 32; bp1 += 32;
    };

    auto TILE = [&](int t, bool stage) {
        const _Float16* Ab = AsF + (t & 3) * (256 * 32) + aoff;
        const _Float16* Bb = BsF + (t & 3) * (256 * 32) + boff;
        if (stage) STAGE((t + 3) & 3);
        f16x8 aF[4], bF[4];
#pragma unroll
        for (int j = 0; j < 4; j++)
            bF[j] = *reinterpret_cast<const f16x8*>(Bb + j * 512);
#pragma unroll
        for (int i = 0; i < 4; i++)
            aF[i] = *reinterpret_cast<const f16x8*>(Ab + i * 512);
        __builtin_amdgcn_s_setprio(1);
#pragma unroll
        for (int i = 0; i < 4; i++)
#pragma unroll
            for (int j = 0; j < 4; j++)
                acc[i][j] = __builtin_amdgcn_mfma_f32_16x16x32_f16(
                    aF[i], bF[j], acc[i][j], 0, 0, 0);
        __builtin_amdgcn_s_setprio(0);
#pragma unroll
        for (int i = 0; i < 4; i++)
            aF[i] = *reinterpret_cast<const f16x8*>(Ab + (4 + i) * 512);
        __builtin_amdgcn_s_setprio(1);
#pragma unroll
        for (int i = 0; i < 4; i++)
#pragma unroll
            for (int j = 0; j < 4; j++)
                acc[4 + i][j] = __builtin_amdgcn_mfma_f32_16x16x32_f16(
                    aF[i], bF[j], acc[4 + i][j], 0, 0, 0);
        __builtin_amdgcn_s_setprio(0);
    };

    const int NK = (HH / 2) / 32;   // 64
    STAGE(0); STAGE(1); STAGE(2);
    BOUNDARY(8);
    for (int t = 0; t <= NK - 4; ++t) {
        TILE(t, true);
        BOUNDARY(8);
    }
    TILE(NK - 3, false); BOUNDARY(4);
    TILE(NK - 2, false); BOUNDARY(0);
    TILE(NK - 1, false);

    float* yk = y + (size_t)kz * TKN * CC;
    int rbase = (lane >> 4) * 4;
#pragma unroll
    for (int mi = 0; mi < 8; mi++) {
#pragma unroll
        for (int ni = 0; ni < 4; ni++) {
            int gcol = n0 + wn + ni * 16 + lrow;
            float bias = (kz == 0) ? b2[(size_t)e * CC + gcol] : 0.f;
#pragma unroll
            for (int r = 0; r < 4; r++) {
                int rowl = m0 + wm + mi * 16 + rbase + r;
                if (rowl < M)
                    yk[(size_t)(segs + rowl) * CC + gcol] = acc[mi][ni][r] + bias;
            }
        }
    }
}

// ---------------------------------------------------------------------------
// Kernel 8: combine. out[t,:] = w0*(y0+y1)[pos0(t),:] + w1*(y0+y1)[pos1(t),:]
// Fully coalesced float4 loads/stores; no atomics.
// ---------------------------------------------------------------------------
__global__ __launch_bounds__(256) void combine_kernel(
    const float* __restrict__ y, const int* __restrict__ posmap,
    const float* __restrict__ topk_w, float* __restrict__ out)
{
    int t = blockIdx.x * 2 + (threadIdx.x >> 7);
    int c = (threadIdx.x & 127) * 8;
    int p0 = posmap[t * 2 + 0], p1 = posmap[t * 2 + 1];
    float wa = topk_w[t * 2 + 0], wb = topk_w[t * 2 + 1];
    const float* y1 = y + (size_t)TKN * CC;
    const float4* a0 = reinterpret_cast<const float4*>(y  + (size_t)p0 * CC + c);
    const float4* a1 = reinterpret_cast<const float4*>(y1 + (size_t)p0 * CC + c);
    const float4* b0 = reinterpret_cast<const float4*>(y  + (size_t)p1 * CC + c);
    const float4* b1 = reinterpret_cast<const float4*>(y1 + (size_t)p1 * CC + c);
    float4 r0, r1;
    float4 av0 = a0[0], av1 = a0[1], aw0 = a1[0], aw1 = a1[1];
    float4 bv0 = b0[0], bv1 = b0[1], bw0 = b1[0], bw1 = b1[1];
    r0.x = wa * (av0.x + aw0.x) + wb * (bv0.x + bw0.x);
    r0.y = wa * (av0.y + aw0.y) + wb * (bv0.y + bw0.y);
    r0.z = wa * (av0.z + aw0.z) + wb * (bv0.z + bw0.z);
    r0.w = wa * (av0.w + aw0.w) + wb * (bv0.w + bw0.w);
    r1.x = wa * (av1.x + aw1.x) + wb * (bv1.x + bw1.x);
    r1.y = wa * (av1.y + aw1.y) + wb * (bv1.y + bw1.y);
    r1.z = wa * (av1.z + aw1.z) + wb * (bv1.z + bw1.z);
    r1.w = wa * (av1.w + aw1.w) + wb * (bv1.w + bw1.w);
    float4* o = reinterpret_cast<float4*>(out + (size_t)t * CC + c);
    o[0] = r0; o[1] = r1;
}

// ---------------------------------------------------------------------------
extern "C" void kernel_launch(void* const* d_in, const int* in_sizes, int n_in,
                              void* d_out, int out_size, void* d_ws, size_t ws_size,
                              hipStream_t stream)
{
    const float* x  = (const float*)d_in[0];
    const float* gn = (const float*)d_in[1];
    const float* gw = (const float*)d_in[2];
    const float* gb = (const float*)d_in[3];
    const float* w1 = (const float*)d_in[4];
    const float* b1 = (const float*)d_in[5];
    const float* w2 = (const float*)d_in[6];
    const float* b2 = (const float*)d_in[7];
    float* out = (float*)d_out;

    // workspace carve (all 16B-aligned; ~208 MB total)
    char* w = (char*)d_ws;
    int*   counts  = (int*)(w + 0);     // 8 ints
    int*   fill    = (int*)(w + 32);    // 8 ints
    int*   offsets = (int*)(w + 64);    // 9 ints
    float* gsum    = (float*)(w + 128); // 8 floats
    size_t off = 256;
    int*   topk_idx = (int*)(w + off);   off += (size_t)TT * 2 * 4;
    float* topk_w   = (float*)(w + off); off += (size_t)TT * 2 * 4;
    int*   rowtok   = (int*)(w + off);   off += (size_t)TKN * 4;
    int*   posmap   = (int*)(w + off);   off += (size_t)TKN * 4;
    _Float16* xg  = (_Float16*)(w + off); off += (size_t)TKN * CC * 2;      // 16 MB
    _Float16* w1t = (_Float16*)(w + off); off += (size_t)EE * HH * CC * 2;  // 64 MB
    _Float16* w2t = (_Float16*)(w + off); off += (size_t)EE * CC * HH * 2;  // 64 MB
    _Float16* hbuf = (_Float16*)(w + off); off += (size_t)TKN * HH * 2;     // 64 MB
    // y0+y1 overlay w1t (dead after gemm1; rewritten by transpose each launch)
    float* ybuf = (float*)w1t;           // 2 * TKN*CC*4 = 64 MB == w1t size

    (void)hipMemsetAsync(d_ws, 0, 256, stream);

    gate_kernel<<<TT / 4, 256, 0, stream>>>(x, gn, gw, gb, topk_idx, topk_w,
                                            counts, gsum);
    // w1 [E,C,H] -> w1t [E,H,C];  w2 [E,H,C] -> w2t [E,C,H]
    transpose_f16_kernel<<<dim3(HH / 64, CC / 64, EE), 256, 0, stream>>>(
        w1, w1t, CC, HH);
    transpose_f16_kernel<<<dim3(CC / 64, HH / 64, EE), 256, 0, stream>>>(
        w2, w2t, HH, CC);
    scan_kernel<<<1, 64, 0, stream>>>(counts, offsets, gsum, out + (size_t)TT * CC);
    scatter_kernel<<<TT / 256, 256, 0, stream>>>(topk_idx, offsets, fill,
                                                 rowtok, posmap);
    gather_kernel<<<TKN / 2, 256, 0, stream>>>(x, rowtok, xg);
    // grid.x=6 covers M_e up to 1536 (E[M_e]=1024, sigma~30; early-exit rest)
    gemm1_kernel<<<dim3(6, HH / 256, EE), 512, 0, stream>>>(xg, w1t, b1,
                                                            offsets, hbuf);
    gemm2_kernel<<<dim3(6, 2 * (CC / 256), EE), 512, 0, stream>>>(
        hbuf, w2t, b2, offsets, ybuf);
    combine_kernel<<<TT / 2, 256, 0, stream>>>(ybuf, posmap, topk_w, out);
}

// Round 3
// 825.815 us; speedup vs baseline: 1.2130x; 1.0611x over previous
//
#include <hip/hip_runtime.h>
#include <math.h>

// Problem constants (from reference): B=2, N=2048, C=1024, H=4096, E=8, K=2
#define TT  4096      // tokens = B*N
#define CC  1024
#define HH  4096
#define EE  8
#define TKN 8192      // T*K total expert-row assignments

typedef _Float16 f16x8 __attribute__((ext_vector_type(8)));
typedef float    f32x4 __attribute__((ext_vector_type(4)));

// async global->LDS DMA, 16B per lane; LDS dest = wave-uniform base + lane*16
#define GLD_LDS16(g, l)                                                        \
    __builtin_amdgcn_global_load_lds(                                          \
        (const __attribute__((address_space(1))) void*)(g),                    \
        (__attribute__((address_space(3))) void*)(l), 16, 0, 0)

// ---------------------------------------------------------------------------
// Kernel 1: gating. One wave per token. fp64 logits so top-2 selection matches
// the numpy reference (selection flips on near-ties would exceed threshold).
// ---------------------------------------------------------------------------
__global__ __launch_bounds__(256) void gate_kernel(
    const float* __restrict__ x, const float* __restrict__ gn,
    const float* __restrict__ gw, const float* __restrict__ gb,
    int* __restrict__ topk_idx, float* __restrict__ topk_w,
    int* __restrict__ counts, float* __restrict__ gsum)
{
    int wave = threadIdx.x >> 6, lane = threadIdx.x & 63;
    int t = blockIdx.x * 4 + wave;
    const float* xrow = x + (size_t)t * CC;

    double acc[EE];
#pragma unroll
    for (int e = 0; e < EE; e++) acc[e] = 0.0;

#pragma unroll
    for (int i = 0; i < CC / 64; i++) {
        int c = i * 64 + lane;
        float xv = xrow[c];                       // coalesced
        const float4* g4 = reinterpret_cast<const float4*>(gw + (size_t)c * EE);
        float4 g0 = g4[0], g1 = g4[1];            // gate_w row c (8 floats)
        double xd = (double)xv;
        acc[0] += xd * (double)g0.x; acc[1] += xd * (double)g0.y;
        acc[2] += xd * (double)g0.z; acc[3] += xd * (double)g0.w;
        acc[4] += xd * (double)g1.x; acc[5] += xd * (double)g1.y;
        acc[6] += xd * (double)g1.z; acc[7] += xd * (double)g1.w;
    }
    // butterfly reduce over 64 lanes; all lanes end with full sums
#pragma unroll
    for (int e = 0; e < EE; e++)
#pragma unroll
        for (int off = 32; off > 0; off >>= 1)
            acc[e] += __shfl_xor(acc[e], off);

    double z[EE], m = -1e300;
#pragma unroll
    for (int e = 0; e < EE; e++) {
        z[e] = acc[e] + (double)gb[e] + (double)gn[(size_t)t * EE + e];
        m = fmax(m, z[e]);
    }
    double p[EE], s = 0.0;
#pragma unroll
    for (int e = 0; e < EE; e++) { p[e] = exp(z[e] - m); s += p[e]; }
    double inv = 1.0 / s;
    double g[EE];
#pragma unroll
    for (int e = 0; e < EE; e++) g[e] = p[e] * inv;

    // top-2, ties -> lower index first (matches jax.lax.top_k)
    int i1 = 0; double v1 = g[0];
#pragma unroll
    for (int e = 1; e < EE; e++) if (g[e] > v1) { v1 = g[e]; i1 = e; }
    int i2 = -1; double v2 = -1.0;
#pragma unroll
    for (int e = 0; e < EE; e++) if (e != i1 && g[e] > v2) { v2 = g[e]; i2 = e; }

    if (lane == 0) {
        topk_idx[t * 2 + 0] = i1; topk_w[t * 2 + 0] = (float)v1;
        topk_idx[t * 2 + 1] = i2; topk_w[t * 2 + 1] = (float)v2;
        atomicAdd(&counts[i1], 1);
        atomicAdd(&counts[i2], 1);
    }

    // per-block gate-sum reduction -> 8 atomics per block
    __shared__ float gp[4][EE];
    if (lane == 0) {
#pragma unroll
        for (int e = 0; e < EE; e++) gp[wave][e] = (float)g[e];
    }
    __syncthreads();
    if (threadIdx.x < EE) {
        float s4 = gp[0][threadIdx.x] + gp[1][threadIdx.x] +
                   gp[2][threadIdx.x] + gp[3][threadIdx.x];
        atomicAdd(&gsum[threadIdx.x], s4);
    }
}

// ---------------------------------------------------------------------------
// Kernel 2: fused transpose + f32->f16 cast for expert weights.
// src: [E][R][Ccols] f32 row-major  ->  dst: [E][Ccols][R] f16 row-major
// ---------------------------------------------------------------------------
__global__ __launch_bounds__(256) void transpose_f16_kernel(
    const float* __restrict__ src, _Float16* __restrict__ dst, int R, int Ccols)
{
    __shared__ float tile[64][65];
    int e = blockIdx.z;
    const float* s = src + (size_t)e * R * Ccols;
    _Float16* d = dst + (size_t)e * R * Ccols;
    int c0 = blockIdx.x * 64, r0 = blockIdx.y * 64;
    int tid = threadIdx.x;

    int lr = tid >> 4;            // 0..15
    int lc = (tid & 15) * 4;      // 0..60
#pragma unroll
    for (int i = 0; i < 4; i++) {
        int r = lr + i * 16;
        float4 v = *reinterpret_cast<const float4*>(
            s + (size_t)(r0 + r) * Ccols + c0 + lc);
        tile[r][lc + 0] = v.x; tile[r][lc + 1] = v.y;
        tile[r][lc + 2] = v.z; tile[r][lc + 3] = v.w;
    }
    __syncthreads();

    int oc = tid >> 2;            // 0..63  (output row = source column)
    int orr = (tid & 3) * 16;     // 0..48
    f16x8 o0, o1;
#pragma unroll
    for (int j = 0; j < 8; j++) o0[j] = (_Float16)tile[orr + j][oc];
#pragma unroll
    for (int j = 0; j < 8; j++) o1[j] = (_Float16)tile[orr + 8 + j][oc];
    *reinterpret_cast<f16x8*>(d + (size_t)(c0 + oc) * R + r0 + orr)     = o0;
    *reinterpret_cast<f16x8*>(d + (size_t)(c0 + oc) * R + r0 + orr + 8) = o1;
}

// ---------------------------------------------------------------------------
// Kernel 3: tiny scan — prefix-sum counts into offsets; load-balance loss.
// ---------------------------------------------------------------------------
__global__ void scan_kernel(const int* __restrict__ counts, int* __restrict__ offsets,
                            const float* __restrict__ gsum, float* __restrict__ loss_out)
{
    if (threadIdx.x == 0) {
        int o = 0;
#pragma unroll
        for (int e = 0; e < EE; e++) { offsets[e] = o; o += counts[e]; }
        offsets[EE] = o;   // == TKN
        float L = 0.f;
#pragma unroll
        for (int e = 0; e < EE; e++) {
            float me = gsum[e] / (float)TT;
            L += me * logf(me + 1e-8f);
        }
        *loss_out = L;
    }
}

// ---------------------------------------------------------------------------
// Kernel 4: scatter token assignments into per-expert contiguous segments.
// posmap[t*2+k] = segment position (inverse map for atomic-free combine).
// ---------------------------------------------------------------------------
__global__ __launch_bounds__(256) void scatter_kernel(
    const int* __restrict__ topk_idx, const int* __restrict__ offsets,
    int* __restrict__ fill, int* __restrict__ rowtok, int* __restrict__ posmap)
{
    int t = blockIdx.x * 256 + threadIdx.x;
#pragma unroll
    for (int k = 0; k < 2; k++) {
        int e = topk_idx[t * 2 + k];
        int pos = offsets[e] + atomicAdd(&fill[e], 1);
        rowtok[pos] = t;
        posmap[t * 2 + k] = pos;
    }
}

// ---------------------------------------------------------------------------
// Kernel 5: pre-gather token rows into segment order + f32->f16 cast.
// ---------------------------------------------------------------------------
__global__ __launch_bounds__(256) void gather_kernel(
    const float* __restrict__ x, const int* __restrict__ rowtok,
    _Float16* __restrict__ xg)
{
    int p = blockIdx.x * 2 + (threadIdx.x >> 7);
    int c = (threadIdx.x & 127) * 8;
    int t = rowtok[p];
    const float4* s = reinterpret_cast<const float4*>(x + (size_t)t * CC + c);
    float4 v0 = s[0], v1 = s[1];
    f16x8 o;
    o[0] = (_Float16)v0.x; o[1] = (_Float16)v0.y;
    o[2] = (_Float16)v0.z; o[3] = (_Float16)v0.w;
    o[4] = (_Float16)v1.x; o[5] = (_Float16)v1.y;
    o[6] = (_Float16)v1.z; o[7] = (_Float16)v1.w;
    *reinterpret_cast<f16x8*>(xg + (size_t)p * CC + c) = o;
}

// ---------------------------------------------------------------------------
// LDS swizzle (both-sides, rule 21): logical byte L in a [rows][32 f16] tile
// maps to phys P = L ^ (((L>>7)&3)<<4)  (row bits 1-2 XOR'd into 16B-slot id).
// - global_load_lds writes linearly at phys -> pre-swizzle the SOURCE column:
//     cc = ((tid&3) ^ ((tid>>3)&3)) * 8 f16
// - frag ds_read_b128 applies the same XOR -> per-lane constant:
//     kgx = (lane>>4) ^ ((lane>>1)&3)
// Result: each 16-lane quarter of a wave covers all 8 16B slots exactly 2x
// (2-way = free, m136) instead of 8 lanes on 2 slots (8-way).
// ---------------------------------------------------------------------------

// ---------------------------------------------------------------------------
// Grouped GEMM 1: h[p,:] = gelu( xg[p,:] @ w1[e] + b1[e] )
// BM=BN=256, BK=32, 512 threads (8 waves 2Mx4N, per-wave 128x64 output).
// Double-buffered LDS (64 KB -> 2 blocks/CU for inter-block latency hiding),
// swizzled staging+reads (conflict-free), 2 MFMA sub-phases with mid-barrier
// + setprio (wave role diversity), stage(t+1) issued at tile start.
// ---------------------------------------------------------------------------
__global__ __launch_bounds__(512) void gemm1_kernel(
    const _Float16* __restrict__ xg, const _Float16* __restrict__ w1t,
    const float* __restrict__ b1, const int* __restrict__ offsets,
    _Float16* __restrict__ h)
{
    // bijective XCD swizzle (nwg = 6*16*8 = 768, %8==0)
    int GX = gridDim.x, GY = gridDim.y;
    int nwg = GX * GY * (int)gridDim.z;
    int f = blockIdx.x + GX * (blockIdx.y + GY * blockIdx.z);
    int cpx = nwg >> 3;
    f = (f & 7) * cpx + (f >> 3);
    int bx = f % GX; int tq = f / GX; int by = tq % GY; int bz = tq / GY;

    int e = bz;
    int segs = offsets[e];
    int M = offsets[e + 1] - segs;
    int m0 = bx * 256;
    if (m0 >= M) return;
    int n0 = by * 256;

    __shared__ __align__(16) _Float16 As[2][256 * 32];   // 2 x 16 KB
    __shared__ __align__(16) _Float16 Bs[2][256 * 32];   // 2 x 16 KB

    int tid = threadIdx.x;
    int wave = tid >> 6, lane = tid & 63;
    int wm = (wave >> 2) * 128, wn = (wave & 3) * 64;
    int lrow = lane & 15;
    int kgx = (lane >> 4) ^ ((lane >> 1) & 3);     // swizzled k-group
    int aoff = (wm + lrow) * 32 + kgx * 8;
    int boff = (wn + lrow) * 32 + kgx * 8;

    const _Float16* wB = w1t + (size_t)e * HH * CC;

    // staging: thread covers phys 16B chunk at row=tid>>2, slot=tid&3;
    // source column pre-swizzled so swizzled reads see logical data.
    int r = tid >> 2;
    int cc = ((tid & 3) ^ ((tid >> 3) & 3)) * 8;
    int rA0 = m0 + r;       if (rA0 >= M) rA0 = M - 1;  // clamp stays in segment
    int rA1 = m0 + 128 + r; if (rA1 >= M) rA1 = M - 1;
    const _Float16* ap0 = xg + (size_t)(segs + rA0) * CC + cc;
    const _Float16* ap1 = xg + (size_t)(segs + rA1) * CC + cc;
    const _Float16* bp0 = wB + (size_t)(n0 + r) * CC + cc;
    const _Float16* bp1 = wB + (size_t)(n0 + 128 + r) * CC + cc;
    int ldst = tid * 8;   // phys elem offset of this thread's chunk

    f32x4 acc[8][4];
#pragma unroll
    for (int i = 0; i < 8; i++)
#pragma unroll
        for (int j = 0; j < 4; j++)
#pragma unroll
            for (int q = 0; q < 4; q++) acc[i][j][q] = 0.f;

    auto STAGE = [&](int b) {
        GLD_LDS16(ap0, &As[b][0] + ldst);
        GLD_LDS16(ap1, &As[b][0] + 4096 + ldst);
        GLD_LDS16(bp0, &Bs[b][0] + ldst);
        GLD_LDS16(bp1, &Bs[b][0] + 4096 + ldst);
        ap0 += 32; ap1 += 32; bp0 += 32; bp1 += 32;
    };

    const int NK = CC / 32;   // 32
    STAGE(0);
    __syncthreads();
    for (int t = 0; t < NK; ++t) {
        int b = t & 1;
        if (t + 1 < NK) STAGE(b ^ 1);     // loads fly under this tile's MFMA
        const _Float16* Ab = &As[b][0] + aoff;
        const _Float16* Bb = &Bs[b][0] + boff;
        f16x8 aF[4], bF[4];
#pragma unroll
        for (int j = 0; j < 4; j++)
            bF[j] = *reinterpret_cast<const f16x8*>(Bb + j * 512);
#pragma unroll
        for (int i = 0; i < 4; i++)
            aF[i] = *reinterpret_cast<const f16x8*>(Ab + i * 512);
        __builtin_amdgcn_s_setprio(1);
#pragma unroll
        for (int i = 0; i < 4; i++)
#pragma unroll
            for (int j = 0; j < 4; j++)
                acc[i][j] = __builtin_amdgcn_mfma_f32_16x16x32_f16(
                    aF[i], bF[j], acc[i][j], 0, 0, 0);
        __builtin_amdgcn_s_setprio(0);
        __builtin_amdgcn_s_barrier();     // sub-phase split (role diversity)
#pragma unroll
        for (int i = 0; i < 4; i++)
            aF[i] = *reinterpret_cast<const f16x8*>(Ab + (4 + i) * 512);
        __builtin_amdgcn_s_setprio(1);
#pragma unroll
        for (int i = 0; i < 4; i++)
#pragma unroll
            for (int j = 0; j < 4; j++)
                acc[4 + i][j] = __builtin_amdgcn_mfma_f32_16x16x32_f16(
                    aF[i], bF[j], acc[4 + i][j], 0, 0, 0);
        __builtin_amdgcn_s_setprio(0);
        __syncthreads();                  // boundary: t+1 staged & visible
    }

    // epilogue: C/D layout col=lane&15, row=(lane>>4)*4+reg  [m89/m91]
    int rbase = (lane >> 4) * 4;
#pragma unroll
    for (int mi = 0; mi < 8; mi++) {
#pragma unroll
        for (int ni = 0; ni < 4; ni++) {
            int gcol = n0 + wn + ni * 16 + lrow;
            float bias = b1[(size_t)e * HH + gcol];
#pragma unroll
            for (int q = 0; q < 4; q++) {
                int rowl = m0 + wm + mi * 16 + rbase + q;
                if (rowl < M) {
                    float v = acc[mi][ni][q] + bias;
                    v = 0.5f * v * (1.0f + erff(v * 0.70710678118654752f)); // exact GELU
                    h[(size_t)(segs + rowl) * HH + gcol] = (_Float16)v;
                }
            }
        }
    }
}

// ---------------------------------------------------------------------------
// Grouped GEMM 2 (split-K=2, no atomics): y[kz][p,:] = h[p, kz*2048:+2048] @
// w2t[e][:, kz-half] (+ b2 when kz==0). BM=128, BN=256, BK=32, 48 KB LDS
// (2-3 blocks/CU). blockIdx.y encodes (kz, n-tile): kz=y>>2, n0=(y&3)*256.
// ---------------------------------------------------------------------------
__global__ __launch_bounds__(512) void gemm2_kernel(
    const _Float16* __restrict__ h, const _Float16* __restrict__ w2t,
    const float* __restrict__ b2, const int* __restrict__ offsets,
    float* __restrict__ y)
{
    int GX = gridDim.x, GY = gridDim.y;
    int nwg = GX * GY * (int)gridDim.z;    // 12*8*8 = 768, %8==0
    int f = blockIdx.x + GX * (blockIdx.y + GY * blockIdx.z);
    int cpx = nwg >> 3;
    f = (f & 7) * cpx + (f >> 3);
    int bx = f % GX; int tq = f / GX; int by = tq % GY; int bz = tq / GY;

    int e = bz;
    int segs = offsets[e];
    int M = offsets[e + 1] - segs;
    int m0 = bx * 128;
    if (m0 >= M) return;
    int kz = by >> 2;
    int n0 = (by & 3) * 256;
    int kbeg = kz * (HH / 2);

    __shared__ __align__(16) _Float16 As[2][128 * 32];   // 2 x 8 KB
    __shared__ __align__(16) _Float16 Bs[2][256 * 32];   // 2 x 16 KB

    int tid = threadIdx.x;
    int wave = tid >> 6, lane = tid & 63;
    int wm = (wave >> 2) * 64, wn = (wave & 3) * 64;
    int lrow = lane & 15;
    int kgx = (lane >> 4) ^ ((lane >> 1) & 3);
    int aoff = (wm + lrow) * 32 + kgx * 8;
    int boff = (wn + lrow) * 32 + kgx * 8;

    const _Float16* wB = w2t + (size_t)e * CC * HH;

    int r = tid >> 2;
    int cc = ((tid & 3) ^ ((tid >> 3) & 3)) * 8;
    int rA = m0 + r; if (rA >= M) rA = M - 1;
    const _Float16* ap  = h  + (size_t)(segs + rA) * HH + kbeg + cc;
    const _Float16* bp0 = wB + (size_t)(n0 + r) * HH + kbeg + cc;
    const _Float16* bp1 = wB + (size_t)(n0 + 128 + r) * HH + kbeg + cc;
    int ldst = tid * 8;

    f32x4 acc[4][4];
#pragma unroll
    for (int i = 0; i < 4; i++)
#pragma unroll
        for (int j = 0; j < 4; j++)
#pragma unroll
            for (int q = 0; q < 4; q++) acc[i][j][q] = 0.f;

    auto STAGE = [&](int b) {
        GLD_LDS16(ap,  &As[b][0] + ldst);
        GLD_LDS16(bp0, &Bs[b][0] + ldst);
        GLD_LDS16(bp1, &Bs[b][0] + 4096 + ldst);
        ap += 32; bp0 += 32; bp1 += 32;
    };

    const int NK = (HH / 2) / 32;   // 64
    STAGE(0);
    __syncthreads();
    for (int t = 0; t < NK; ++t) {
        int b = t & 1;
        if (t + 1 < NK) STAGE(b ^ 1);
        const _Float16* Ab = &As[b][0] + aoff;
        const _Float16* Bb = &Bs[b][0] + boff;
        f16x8 aF[4], bF[4];
#pragma unroll
        for (int j = 0; j < 4; j++)
            bF[j] = *reinterpret_cast<const f16x8*>(Bb + j * 512);
#pragma unroll
        for (int i = 0; i < 4; i++)
            aF[i] = *reinterpret_cast<const f16x8*>(Ab + i * 512);
        __builtin_amdgcn_s_setprio(1);
#pragma unroll
        for (int i = 0; i < 2; i++)
#pragma unroll
            for (int j = 0; j < 4; j++)
                acc[i][j] = __builtin_amdgcn_mfma_f32_16x16x32_f16(
                    aF[i], bF[j], acc[i][j], 0, 0, 0);
        __builtin_amdgcn_s_setprio(0);
        __builtin_amdgcn_s_barrier();
        __builtin_amdgcn_s_setprio(1);
#pragma unroll
        for (int i = 2; i < 4; i++)
#pragma unroll
            for (int j = 0; j < 4; j++)
                acc[i][j] = __builtin_amdgcn_mfma_f32_16x16x32_f16(
                    aF[i], bF[j], acc[i][j], 0, 0, 0);
        __builtin_amdgcn_s_setprio(0);
        __syncthreads();
    }

    float* yk = y + (size_t)kz * TKN * CC;
    int rbase = (lane >> 4) * 4;
#pragma unroll
    for (int mi = 0; mi < 4; mi++) {
#pragma unroll
        for (int ni = 0; ni < 4; ni++) {
            int gcol = n0 + wn + ni * 16 + lrow;
            float bias = (kz == 0) ? b2[(size_t)e * CC + gcol] : 0.f;
#pragma unroll
            for (int q = 0; q < 4; q++) {
                int rowl = m0 + wm + mi * 16 + rbase + q;
                if (rowl < M)
                    yk[(size_t)(segs + rowl) * CC + gcol] = acc[mi][ni][q] + bias;
            }
        }
    }
}

// ---------------------------------------------------------------------------
// Kernel 8: combine. out[t,:] = w0*(y0+y1)[pos0(t),:] + w1*(y0+y1)[pos1(t),:]
// Fully coalesced float4 loads/stores; no atomics.
// ---------------------------------------------------------------------------
__global__ __launch_bounds__(256) void combine_kernel(
    const float* __restrict__ y, const int* __restrict__ posmap,
    const float* __restrict__ topk_w, float* __restrict__ out)
{
    int t = blockIdx.x * 2 + (threadIdx.x >> 7);
    int c = (threadIdx.x & 127) * 8;
    int p0 = posmap[t * 2 + 0], p1 = posmap[t * 2 + 1];
    float wa = topk_w[t * 2 + 0], wb = topk_w[t * 2 + 1];
    const float* y1 = y + (size_t)TKN * CC;
    const float4* a0 = reinterpret_cast<const float4*>(y  + (size_t)p0 * CC + c);
    const float4* a1 = reinterpret_cast<const float4*>(y1 + (size_t)p0 * CC + c);
    const float4* b0 = reinterpret_cast<const float4*>(y  + (size_t)p1 * CC + c);
    const float4* b1 = reinterpret_cast<const float4*>(y1 + (size_t)p1 * CC + c);
    float4 r0, r1;
    float4 av0 = a0[0], av1 = a0[1], aw0 = a1[0], aw1 = a1[1];
    float4 bv0 = b0[0], bv1 = b0[1], bw0 = b1[0], bw1 = b1[1];
    r0.x = wa * (av0.x + aw0.x) + wb * (bv0.x + bw0.x);
    r0.y = wa * (av0.y + aw0.y) + wb * (bv0.y + bw0.y);
    r0.z = wa * (av0.z + aw0.z) + wb * (bv0.z + bw0.z);
    r0.w = wa * (av0.w + aw0.w) + wb * (bv0.w + bw0.w);
    r1.x = wa * (av1.x + aw1.x) + wb * (bv1.x + bw1.x);
    r1.y = wa * (av1.y + aw1.y) + wb * (bv1.y + bw1.y);
    r1.z = wa * (av1.z + aw1.z) + wb * (bv1.z + bw1.z);
    r1.w = wa * (av1.w + aw1.w) + wb * (bv1.w + bw1.w);
    float4* o = reinterpret_cast<float4*>(out + (size_t)t * CC + c);
    o[0] = r0; o[1] = r1;
}

// ---------------------------------------------------------------------------
extern "C" void kernel_launch(void* const* d_in, const int* in_sizes, int n_in,
                              void* d_out, int out_size, void* d_ws, size_t ws_size,
                              hipStream_t stream)
{
    const float* x  = (const float*)d_in[0];
    const float* gn = (const float*)d_in[1];
    const float* gw = (const float*)d_in[2];
    const float* gb = (const float*)d_in[3];
    const float* w1 = (const float*)d_in[4];
    const float* b1 = (const float*)d_in[5];
    const float* w2 = (const float*)d_in[6];
    const float* b2 = (const float*)d_in[7];
    float* out = (float*)d_out;

    // workspace carve (all 16B-aligned; ~208 MB total)
    char* w = (char*)d_ws;
    int*   counts  = (int*)(w + 0);     // 8 ints
    int*   fill    = (int*)(w + 32);    // 8 ints
    int*   offsets = (int*)(w + 64);    // 9 ints
    float* gsum    = (float*)(w + 128); // 8 floats
    size_t off = 256;
    int*   topk_idx = (int*)(w + off);   off += (size_t)TT * 2 * 4;
    float* topk_w   = (float*)(w + off); off += (size_t)TT * 2 * 4;
    int*   rowtok   = (int*)(w + off);   off += (size_t)TKN * 4;
    int*   posmap   = (int*)(w + off);   off += (size_t)TKN * 4;
    _Float16* xg  = (_Float16*)(w + off); off += (size_t)TKN * CC * 2;      // 16 MB
    _Float16* w1t = (_Float16*)(w + off); off += (size_t)EE * HH * CC * 2;  // 64 MB
    _Float16* w2t = (_Float16*)(w + off); off += (size_t)EE * CC * HH * 2;  // 64 MB
    _Float16* hbuf = (_Float16*)(w + off); off += (size_t)TKN * HH * 2;     // 64 MB
    // y0+y1 overlay w1t (dead after gemm1; rewritten by transpose each launch)
    float* ybuf = (float*)w1t;           // 2 * TKN*CC*4 = 64 MB == w1t size

    (void)hipMemsetAsync(d_ws, 0, 256, stream);

    gate_kernel<<<TT / 4, 256, 0, stream>>>(x, gn, gw, gb, topk_idx, topk_w,
                                            counts, gsum);
    // w1 [E,C,H] -> w1t [E,H,C];  w2 [E,H,C] -> w2t [E,C,H]
    transpose_f16_kernel<<<dim3(HH / 64, CC / 64, EE), 256, 0, stream>>>(
        w1, w1t, CC, HH);
    transpose_f16_kernel<<<dim3(CC / 64, HH / 64, EE), 256, 0, stream>>>(
        w2, w2t, HH, CC);
    scan_kernel<<<1, 64, 0, stream>>>(counts, offsets, gsum, out + (size_t)TT * CC);
    scatter_kernel<<<TT / 256, 256, 0, stream>>>(topk_idx, offsets, fill,
                                                 rowtok, posmap);
    gather_kernel<<<TKN / 2, 256, 0, stream>>>(x, rowtok, xg);
    // grid.x=6 covers M_e up to 1536 (E[M_e]=1024, sigma~30; early-exit rest)
    gemm1_kernel<<<dim3(6, HH / 256, EE), 512, 0, stream>>>(xg, w1t, b1,
                                                            offsets, hbuf);
    gemm2_kernel<<<dim3(12, 2 * (CC / 256), EE), 512, 0, stream>>>(
        hbuf, w2t, b2, offsets, ybuf);
    combine_kernel<<<TT / 2, 256, 0, stream>>>(ybuf, posmap, topk_w, out);
}